// Round 3
// baseline (25.867 us; speedup 1.0000x reference)
//
#include <hip/hip_runtime.h>
#include <math.h>

#define EPSV   1e-4f
#define DSCALE 1.25f   // 1/(1-0.2)

#define XSTR 29        // padded row stride (breaks stride-28 bank conflicts)
#define XIMG 812       // 28*29 floats per image

// One block per (b,c). Computes channel-c conv over ALL batches (for BN stats),
// pools own batch, applies BN/ELU/dropout, builds T = (f.W1)^T Xg, and
// atomically accumulates mu_out / Sigma_out partials into d_out.
__global__ __launch_bounds__(256) void kFused(
    const float* __restrict__ x,      // [16,28,28,1]
    const int*   __restrict__ dmask,  // [16,12,12,16]
    const float* __restrict__ wconv,  // [5,5,1,16]
    const float* __restrict__ wsconv, // [16]
    const float* __restrict__ wfc,    // [2304,10]
    const float* __restrict__ wsfc,   // [10]
    float*       __restrict__ out)    // [160 mu | 1600 Sigma]
{
    __shared__ float xa_s[16 * XIMG];   // all 16 images, padded rows
    __shared__ float w_s[25];
    __shared__ float mu_s[576];         // own-batch conv out
    __shared__ float ra_s[256], rb_s[256];
    __shared__ float f_s[144], mud_s[144];
    __shared__ int   I_s[144];
    __shared__ float W2_s[1440];        // spatial-major fc rows (mu_out path)
    __shared__ float fW_s[1440];        // channel-major fc rows, scaled by f
    __shared__ float Xg_s[3600];        // [q][p] gathered argmax patches
    __shared__ float T_s[250];          // [p][u]
    __shared__ float stat_s[4];
    __shared__ float spfc_s[10];

    const int bc = blockIdx.x, b = bc >> 4, c = bc & 15, t = threadIdx.x;

    // ---- stage all global inputs into LDS ----
    for (int j = t; j < 12544; j += 256) {
        const int bb = j / 784, rem = j - bb * 784;
        const int r = rem / 28, col = rem - r * 28;
        xa_s[bb * XIMG + r * XSTR + col] = x[j];
    }
    if (t < 25) w_s[t] = wconv[t * 16 + c];
    for (int j = t; j < 1440; j += 256) {
        const int q = j / 10, u = j - q * 10;
        W2_s[j] = wfc[(q * 16 + c) * 10 + u];   // row q*16+c (NHWC flatten)
        fW_s[j] = wfc[c * 1440 + j];            // row c*144+q (W1 view)
    }
    if (t < 10) spfc_s[t] = log1pf(expf(wsfc[t]));
    __syncthreads();

    // ---- conv (channel c) over all batches: 768 half-row tasks, 3/thread ----
    float s_acc = 0.f, q_acc = 0.f;
    for (int task = t; task < 768; task += 256) {
        const int bb = task / 48;
        const int hr = task - bb * 48;
        const int row = hr >> 1;
        const int x0 = (hr & 1) * 12;
        const float* xb = &xa_s[bb * XIMG + row * XSTR + x0];
        float acc[12];
#pragma unroll
        for (int j = 0; j < 12; j++) acc[j] = 0.f;
#pragma unroll
        for (int dy = 0; dy < 5; dy++) {
            const float* xr = xb + dy * XSTR;
            float rr[16];
#pragma unroll
            for (int j = 0; j < 16; j++) rr[j] = xr[j];
#pragma unroll
            for (int dx = 0; dx < 5; dx++) {
                const float wv = w_s[dy * 5 + dx];
#pragma unroll
                for (int j = 0; j < 12; j++)
                    acc[j] = fmaf(rr[j + dx], wv, acc[j]);
            }
        }
        const int obase = row * 24 + x0;
        if (bb == b) {
#pragma unroll
            for (int j = 0; j < 12; j++) mu_s[obase + j] = acc[j];
        }
#pragma unroll
        for (int j = 0; j < 12; j++) {
            s_acc += acc[j];
            q_acc = fmaf(acc[j], acc[j], q_acc);
        }
    }
    ra_s[t] = s_acc; rb_s[t] = q_acc;
    __syncthreads();
    for (int s = 128; s > 0; s >>= 1) {
        if (t < s) { ra_s[t] += ra_s[t + s]; rb_s[t] += rb_s[t + s]; }
        __syncthreads();
    }
    if (t == 0) {
        const float mean = ra_s[0] * (1.f / 9216.f);
        const float var  = rb_s[0] * (1.f / 9216.f) - mean * mean;
        stat_s[0] = mean;
        stat_s[1] = 1.f / sqrtf(var + EPSV);
        stat_s[2] = log1pf(expf(wsconv[c])) / (var + EPSV);  // sc
    }
    __syncthreads();

    // ---- pool (raw values: BN monotone, first-max ties) + BN + ELU + drop ----
    float trv = 0.f, mmv = 0.f;
    if (t < 144) {
        const int h = t / 12, w2 = t - h * 12;
        const int y0 = 2 * h, x0 = 2 * w2;
        const int i0 = y0 * 24 + x0;
        const float v00 = mu_s[i0], v01 = mu_s[i0 + 1];
        const float v10 = mu_s[i0 + 24], v11 = mu_s[i0 + 25];
        float best = v00; int arg = 0;
        if (v01 > best) { best = v01; arg = 1; }
        if (v10 > best) { best = v10; arg = 2; }
        if (v11 > best) { best = v11; arg = 3; }
        const int yy = y0 + (arg >> 1), xx = x0 + (arg & 1);
        const int i29 = yy * XSTR + xx;
        const float vn = (best - stat_s[0]) * stat_s[1];
        const float m = (dmask[((b * 12 + h) * 12 + w2) * 16 + c] != 0) ? 1.f : 0.f;
        const float g  = vn > 0.f ? 1.f : expf(vn);
        const float el = vn > 0.f ? vn  : expm1f(vn);
        const float fq = DSCALE * m * g;
        const float md = DSCALE * m * el;
        f_s[t] = fq; mud_s[t] = md; I_s[t] = i29;
        const float* xo = &xa_s[b * XIMG + i29];
        float pn = 0.f;
#pragma unroll
        for (int dy = 0; dy < 5; dy++)
#pragma unroll
            for (int dx = 0; dx < 5; dx++) {
                const float v = xo[dy * XSTR + dx];
                pn = fmaf(v, v, pn);
            }
        trv = stat_s[2] * fq * fq * pn;   // sc * f^2 * ||patch||^2
        mmv = md * md;
    }
    ra_s[t] = trv; rb_s[t] = mmv;
    __syncthreads();

    // ---- scale W1 rows by f; gather argmax patches ----
    for (int j = t; j < 1440; j += 256) fW_s[j] *= f_s[j / 10];
    {
        const int bo = b * XIMG;
        for (int e = t; e < 3600; e += 256) {
            const int q = e / 25, p = e - q * 25;
            Xg_s[e] = xa_s[bo + I_s[q] + (p / 5) * XSTR + (p % 5)];
        }
    }
    __syncthreads();
    for (int s = 128; s > 0; s >>= 1) {
        if (t < s) { ra_s[t] += ra_s[t + s]; rb_s[t] += rb_s[t + s]; }
        __syncthreads();
    }
    // ra_s[0] = tr_c, rb_s[0] = mm_c (this channel's share of trace & mu.mu)

    // ---- T[p,u] = sum_q fW[q,u] * Xg[q,p] ----
    if (t < 250) {
        const int p = t / 10, u = t - p * 10;
        float acc = 0.f;
#pragma unroll 8
        for (int q = 0; q < 144; q++)
            acc = fmaf(fW_s[q * 10 + u], Xg_s[q * 25 + p], acc);
        T_s[t] = acc;
    }
    __syncthreads();

    // ---- accumulate outputs ----
    if (t < 100) {
        const int u = t / 10, v = t - u * 10;
        float acc = 0.f;
#pragma unroll
        for (int p = 0; p < 25; p++)
            acc = fmaf(T_s[p * 10 + u], T_s[p * 10 + v], acc);
        float val = stat_s[2] * acc;                       // sc * (T^T T)
        if (u == v) val += spfc_s[u] * (ra_s[0] + rb_s[0]); // diag share
        atomicAdd(&out[160 + b * 100 + t], val);
    } else if (t < 110) {
        const int u = t - 100;
        float acc = 0.f;
#pragma unroll 8
        for (int q = 0; q < 144; q++)
            acc = fmaf(mud_s[q], W2_s[q * 10 + u], acc);
        atomicAdd(&out[b * 10 + u], acc);
    }
}

extern "C" void kernel_launch(void* const* d_in, const int* in_sizes, int n_in,
                              void* d_out, int out_size, void* d_ws, size_t ws_size,
                              hipStream_t stream) {
    const float* x      = (const float*)d_in[0];
    const int*   dmask  = (const int*)d_in[1];
    const float* wconv  = (const float*)d_in[2];
    const float* wsconv = (const float*)d_in[3];
    const float* wfc    = (const float*)d_in[4];
    const float* wsfc   = (const float*)d_in[5];
    float* out = (float*)d_out;

    // atomics accumulate into out -> must zero it inside the captured graph
    hipMemsetAsync(out, 0, (size_t)out_size * sizeof(float), stream);
    kFused<<<256, 256, 0, stream>>>(x, dmask, wconv, wsconv, wfc, wsfc, out);
}